// Round 8
// baseline (173.708 us; speedup 1.0000x reference)
//
#include <hip/hip_runtime.h>

// DSQG attention, J=12 causal offsets, f32.
// R9: R8's software-pipelined j-loop, made unroll-proof. R8 core-dumped;
// best-fit mechanism: if the outer 4-iter loop didn't fully unroll, the
// ping-pong state qrP[s]/krP[s] (runtime s) lands in scratch, and asm "=v"
// outputs homed in scratch are copied reg->scratch BEFORE the pending
// global_load lands -> the late hardware write hits a reassigned physical
// VGPR -> random register (incl. address) corruption -> GPU fault.
// Fixes:
//   * 4 iterations MACRO-instantiated with NAMED A/B state (qrA..zlA /
//     qrB..zlB) — zero runtime indexing, asm dests always register-homed.
//   * pbh/pbs/pgn asm-pinned before __syncthreads -> their loads complete
//     pre-barrier -> vmcnt ledger starts at 0 (no reliance on barrier drain).
// Pipeline (per iteration j, 4 total):
//   top:  vmcnt(3) [A(j) q+7k ready; y,z + store(j-1) outstanding] (j0: 2)
//   body: dot(j) -> issue B(j) [7 v + vx] -> issue A(j+1) [10] -> DPP+softmax
//   tail: vmcnt(10) [only A(j+1) remains] (j3: 0) -> rotation+sum+store
// Carried from R7b: 80-row k/v LDS window serves d in {1,2,4,8,16}; lane-
// parallel rotation (lane t8 owns offset 4+t8); DPP 16-lane allreduce;
// max-free softmax; v_rcp normalize; XCD swizzle.

namespace {

constexpr int J   = 12;
constexpr int B_  = 2;
constexpr int H_  = 16;
constexpr int N_  = 4096;
constexpr int HD_ = 64;
constexpr int OFFS[J] = {1, 2, 4, 8, 16, 64, 96, 192, 384, 512, 768, 1024};
constexpr int T_  = 64;   // positions per block
constexpr int W_  = 80;   // staged rows: [P-16, P+63]

using f32x4 = __attribute__((ext_vector_type(4))) float;
using f32x2 = __attribute__((ext_vector_type(2))) float;

#define GLOAD4(dst, off, base)                                              \
    asm volatile("global_load_dwordx4 %0, %1, %2"                           \
                 : "=v"(dst) : "v"(off), "s"(base) : "memory")
#define GLOAD2(dst, off, base)                                              \
    asm volatile("global_load_dwordx2 %0, %1, %2"                           \
                 : "=v"(dst) : "v"(off), "s"(base) : "memory")

#define VMWAIT(N)                                                           \
    asm volatile("s_waitcnt vmcnt(" #N ")" ::: "memory");                   \
    __builtin_amdgcn_sched_barrier(0)

// p += dpp_mov(p); CTRL must be an ICE, hence the template.
template <int CTRL>
__device__ __forceinline__ float dpp_add(float x) {
    int s = __builtin_amdgcn_update_dpp(0, __builtin_bit_cast(int, x),
                                        CTRL, 0xF, 0xF, false);
    return x + __builtin_bit_cast(float, s);
}

// A-batch for position nn: q, 7 large-d k, y, z — 10 vmem ops in this exact
// order (the vmcnt ledger depends on it). Uses gbl/qb/kb/yb/zb/dl from scope.
#define ISSUEA(nn, QR, KR, YP, ZL) do {                                     \
    const int nA_ = (nn);                                                   \
    const uint32_t rbA_ = ((uint32_t)nA_ << 8) + gbl;                       \
    GLOAD4(QR, rbA_, qb);                                                   \
    _Pragma("unroll")                                                       \
    for (int i = 5; i < J; ++i) {                                           \
        const uint32_t oA_ = (nA_ >= OFFS[i])                               \
            ? (rbA_ - ((uint32_t)OFFS[i] << 8)) : gbl;                      \
        GLOAD4(KR[i - 5], oA_, kb);                                         \
    }                                                                       \
    const uint32_t nb8A_ = (uint32_t)nA_ << 3;                              \
    GLOAD2(YP, nb8A_, yb);                                                  \
    const uint32_t zoA_ = (nA_ >= dl) ? ((uint32_t)(nA_ - dl) << 3) : 0u;   \
    GLOAD2(ZL, zoA_, zb);                                                   \
} while (0)

// One pipeline iteration. TOPN/TAILN are literal vmcnt counts; PREF is a
// literal 0/1. All state names are concrete variables — no runtime indexing.
#define ITERBODY(NVAL, TOPN, TAILN, PREF, QR, KR, YP, ZL, QRN, KRN, YPN, ZLN) \
do {                                                                        \
    const int n_ = (NVAL);                                                  \
    const uint32_t rowb_ = ((uint32_t)n_ << 8) + gbl;                       \
    VMWAIT(TOPN);                              /* q+7k of A(j) ready */     \
    const int rbase_ = n_ - P + 16;            /* in [16, 79] */            \
    float p_[J];                                                            \
    _Pragma("unroll")                                                       \
    for (int i = 0; i < 5; ++i) {                                           \
        const f32x4 kk  = kS[(rbase_ - OFFS[i]) * 16 + grp];                \
        const f32x4 seg = seS[i * 16 + grp];                                \
        float t = QR.x * (kk.x + seg.x);                                    \
        t = fmaf(QR.y, kk.y + seg.y, t);                                    \
        t = fmaf(QR.z, kk.z + seg.z, t);                                    \
        p_[i] = fmaf(QR.w, kk.w + seg.w, t);                                \
    }                                                                       \
    _Pragma("unroll")                                                       \
    for (int i = 5; i < J; ++i) {                                           \
        const f32x4 kk  = KR[i - 5];                                        \
        const f32x4 seg = seS[i * 16 + grp];                                \
        float t = QR.x * (kk.x + seg.x);                                    \
        t = fmaf(QR.y, kk.y + seg.y, t);                                    \
        t = fmaf(QR.z, kk.z + seg.z, t);                                    \
        p_[i] = fmaf(QR.w, kk.w + seg.w, t);                                \
    }                                                                       \
    /* batch B(j): 7 large-d v + vx (k registers just died) */              \
    f32x4 vr_[7];                                                           \
    _Pragma("unroll")                                                       \
    for (int i = 5; i < J; ++i) {                                           \
        const uint32_t oB_ = (n_ >= OFFS[i])                                \
            ? (rowb_ - ((uint32_t)OFFS[i] << 8)) : gbl;                     \
        GLOAD4(vr_[i - 5], oB_, vb);                                        \
    }                                                                       \
    f32x4 vx_;                                                              \
    const uint32_t vxo_ = (n_ >= dl) ? ((uint32_t)(n_ - dl) << 8) : 0u;     \
    GLOAD4(vx_, vxo_, vb);                                                  \
    if (PREF) { ISSUEA(n_ + 4, QRN, KRN, YPN, ZLN); }                       \
    /* 16-lane allreduce (pure VALU DPP); covers B + A(j+1) latency */      \
    _Pragma("unroll")                                                       \
    for (int i = 0; i < J; ++i) {                                           \
        p_[i] = dpp_add<0xB1>(p_[i]);   /* quad_perm [1,0,3,2] : xor 1 */   \
        p_[i] = dpp_add<0x4E>(p_[i]);   /* quad_perm [2,3,0,1] : xor 2 */   \
        p_[i] = dpp_add<0x124>(p_[i]);  /* row_ror:4 */                     \
        p_[i] = dpp_add<0x128>(p_[i]);  /* row_ror:8 */                     \
    }                                                                       \
    float e_[J];                                                            \
    float sum_ = 0.f;                                                       \
    _Pragma("unroll")                                                       \
    for (int i = 0; i < J; ++i) {                                           \
        const float si = fmaf(p_[i], 0.125f, pbh[i]);                       \
        e_[i] = (n_ >= OFFS[i]) ? __expf(si) : 0.f;                         \
        sum_ += e_[i];                                                      \
    }                                                                       \
    VMWAIT(TAILN);                 /* iter-j vmem done; A(j+1) in flight */ \
    /* lane-parallel rotation: lane handles offset i = 4 + t8 */            \
    const float s01_ = (t8 & 1) ? e_[5]  : e_[4];                           \
    const float s23_ = (t8 & 1) ? e_[7]  : e_[6];                           \
    const float s45_ = (t8 & 1) ? e_[9]  : e_[8];                           \
    const float s67_ = (t8 & 1) ? e_[11] : e_[10];                          \
    const float sA_  = (t8 & 2) ? s23_ : s01_;                              \
    const float sB_  = (t8 & 2) ? s67_ : s45_;                              \
    const float esel_ = (t8 & 4) ? sB_ : sA_;                               \
    const float th0_ = fmaf(pgn.x, YP.x * ZL.x, pbs.x);                     \
    const float th1_ = fmaf(pgn.y, YP.y * ZL.y, pbs.y);                     \
    const float c0_ = __cosf(th0_), s0_ = __sinf(th0_);                     \
    const float c1_ = __cosf(th1_), s1_ = __sinf(th1_);                     \
    f32x4 cx_;                                                              \
    cx_.x = esel_ * (c0_ * vx_.x - s0_ * vx_.y);                            \
    cx_.y = esel_ * (s0_ * vx_.x + c0_ * vx_.y);                            \
    cx_.z = esel_ * (c1_ * vx_.z - s1_ * vx_.w);                            \
    cx_.w = esel_ * (s1_ * vx_.z + c1_ * vx_.w);                            \
    cx_.x = dpp_add<0xB1>(cx_.x);  cx_.y = dpp_add<0xB1>(cx_.y);            \
    cx_.z = dpp_add<0xB1>(cx_.z);  cx_.w = dpp_add<0xB1>(cx_.w);            \
    cx_.x = dpp_add<0x4E>(cx_.x);  cx_.y = dpp_add<0x4E>(cx_.y);            \
    cx_.z = dpp_add<0x4E>(cx_.z);  cx_.w = dpp_add<0x4E>(cx_.w);            \
    cx_.x = dpp_add<0x124>(cx_.x); cx_.y = dpp_add<0x124>(cx_.y);           \
    cx_.z = dpp_add<0x124>(cx_.z); cx_.w = dpp_add<0x124>(cx_.w);           \
    /* weighted sum: i<5 from LDS window, i>=5 from regs */                 \
    float4 accl_ = make_float4(0.f, 0.f, 0.f, 0.f);                         \
    _Pragma("unroll")                                                       \
    for (int i = 0; i < 4; ++i) {                                           \
        const f32x4 vv = vS[(rbase_ - OFFS[i]) * 16 + grp];                 \
        accl_.x = fmaf(e_[i], vv.x, accl_.x);                               \
        accl_.y = fmaf(e_[i], vv.y, accl_.y);                               \
        accl_.z = fmaf(e_[i], vv.z, accl_.z);                               \
        accl_.w = fmaf(e_[i], vv.w, accl_.w);                               \
    }                                                                       \
    float4 acch_ = accl_;                                                   \
    {                                                                       \
        const f32x4 vv = vS[(rbase_ - 16) * 16 + grp];                      \
        acch_.x = fmaf(e_[4], vv.x, acch_.x);                               \
        acch_.y = fmaf(e_[4], vv.y, acch_.y);                               \
        acch_.z = fmaf(e_[4], vv.z, acch_.z);                               \
        acch_.w = fmaf(e_[4], vv.w, acch_.w);                               \
    }                                                                       \
    _Pragma("unroll")                                                       \
    for (int i = 5; i < J; ++i) {                                           \
        acch_.x = fmaf(e_[i], vr_[i - 5].x, acch_.x);                       \
        acch_.y = fmaf(e_[i], vr_[i - 5].y, acch_.y);                       \
        acch_.z = fmaf(e_[i], vr_[i - 5].z, acch_.z);                       \
        acch_.w = fmaf(e_[i], vr_[i - 5].w, acch_.w);                       \
    }                                                                       \
    const bool lo_ = (grp == 0);                                            \
    float4 acc_;                                                            \
    acc_.x = lo_ ? accl_.x + cx_.x : acch_.x;                               \
    acc_.y = lo_ ? accl_.y + cx_.y : acch_.y;                               \
    acc_.z = lo_ ? accl_.z + cx_.z : acch_.z;                               \
    acc_.w = lo_ ? accl_.w + cx_.w : acch_.w;                               \
    float4 res_;                                                            \
    if (n_ >= 1) {                                                          \
        const float inv_ = __builtin_amdgcn_rcpf(sum_);                     \
        res_ = make_float4(acc_.x * inv_, acc_.y * inv_,                    \
                           acc_.z * inv_, acc_.w * inv_);                   \
    } else {                                                                \
        res_ = make_float4(0.f, 0.f, 0.f, 0.f);                             \
    }                                                                       \
    *(float4*)(ob + rowb_) = res_;   /* newest vmem op; bound by asm */     \
} while (0)

__global__ __launch_bounds__(256, 3) void dsqg_kernel(
    const float* __restrict__ q, const float* __restrict__ k,
    const float* __restrict__ v, const float* __restrict__ pb,
    const float* __restrict__ se, const float* __restrict__ phase_base,
    const float* __restrict__ phase_gain, const float* __restrict__ y_pre,
    const float* __restrict__ z_pre, float* __restrict__ out)
{
    __shared__ f32x4 kS[W_ * 16];     // 20 KB: k rows [P-16, P+63]
    __shared__ f32x4 vS[W_ * 16];     // 20 KB: v rows [P-16, P+63]
    __shared__ f32x4 seS[J * 16];     //  3 KB: se fragments [i][grp]

    // XCD-locality swizzle: contiguous work range per XCD.
    const int raw = blockIdx.x;
    const int per = gridDim.x >> 3;            // 2048/8 = 256
    const int wid = (raw & 7) * per + (raw >> 3);

    const int bh  = wid >> 6;                  // 64 blocks per (b,h)
    const int blk = wid & 63;
    const int h   = bh & (H_ - 1);
    const int P   = blk * T_;                  // first position of this block

    const int tid  = threadIdx.x;
    const int lane = tid & 63;
    const int wave = tid >> 6;
    const int grp  = lane & 15;                // lane within position group
    const int sub  = lane >> 4;                // position-within-quad

    if (tid < J * 16) seS[tid] = ((const f32x4*)se)[tid];

    // uniform (SGPR) per-(b,h) base pointers
    const size_t bhbytes = (size_t)bh * (N_ * HD_ * 4);
    const char* qb = (const char*)q + bhbytes;
    const char* kb = (const char*)k + bhbytes;
    const char* vb = (const char*)v + bhbytes;
    char*       ob = (char*)out + bhbytes;
    const char* yb = (const char*)y_pre + (size_t)bh * (N_ * 8);
    const char* zb = (const char*)z_pre + (size_t)bh * (N_ * 8);

    // ---- stage k/v window into LDS (coalesced; 5 iters x 256 thr x 16 B) ----
    {
        const int r0 = P - 16;
#pragma unroll
        for (int t = 0; t < (W_ * 16) / 256; ++t) {
            const int idx = t * 256 + tid;     // 0..1279 (float4 index)
            const int row = idx >> 4;
            const int col = idx & 15;
            int gr = r0 + row;                 // clamp for block 0 only
            gr = gr < 0 ? 0 : gr;
            const uint32_t go = ((uint32_t)gr << 8) + ((uint32_t)col << 4);
            kS[idx] = *(const f32x4*)(kb + go);
            vS[idx] = *(const f32x4*)(vb + go);
        }
    }

    // hoisted per-lane rotation offset dl = OFFS[4 + (grp&7)] via tree
    const int t8  = grp & 7;
    const int d01 = (t8 & 1) ? 64   : 16;
    const int d23 = (t8 & 1) ? 192  : 96;
    const int d45 = (t8 & 1) ? 512  : 384;
    const int d67 = (t8 & 1) ? 1024 : 768;
    const int dA  = (t8 & 2) ? d23 : d01;
    const int dB  = (t8 & 2) ? d67 : d45;
    const int dl  = (t8 & 4) ? dB : dA;

    const uint32_t pofs = (uint32_t)(t8 * H_ + h) << 3;    // [pi][h][2] f32
    const f32x2 pbs = *(const f32x2*)((const char*)phase_base + pofs);
    const f32x2 pgn = *(const f32x2*)((const char*)phase_gain + pofs);
    float pbh[J];
#pragma unroll
    for (int i = 0; i < J; ++i) pbh[i] = pb[i * H_ + h];

    // Force all compiler-tracked loads above to COMPLETE here, so the asm
    // vmcnt ledger below starts at zero (no reliance on barrier drain).
    asm volatile("" :: "v"(pbs.x), "v"(pbs.y), "v"(pgn.x), "v"(pgn.y));
    asm volatile("" :: "v"(pbh[0]), "v"(pbh[1]), "v"(pbh[2]), "v"(pbh[3]),
                       "v"(pbh[4]), "v"(pbh[5]), "v"(pbh[6]), "v"(pbh[7]),
                       "v"(pbh[8]), "v"(pbh[9]), "v"(pbh[10]), "v"(pbh[11]));

    __syncthreads();    // staging + seS visible

    const uint32_t gbl = (uint32_t)grp << 4;
    const int n0 = P + wave * 16 + sub;

    // ---- software pipeline: named ping-pong A-state, macro-instantiated ----
    f32x4 qrA, qrB;
    f32x4 krA[7], krB[7];
    f32x2 ypA, ypB, zlA, zlB;

    ISSUEA(n0, qrA, krA, ypA, zlA);

    ITERBODY(n0,      2, 10, 1, qrA, krA, ypA, zlA, qrB, krB, ypB, zlB);
    ITERBODY(n0 + 4,  3, 10, 1, qrB, krB, ypB, zlB, qrA, krA, ypA, zlA);
    ITERBODY(n0 + 8,  3, 10, 1, qrA, krA, ypA, zlA, qrB, krB, ypB, zlB);
    ITERBODY(n0 + 12, 3,  0, 0, qrB, krB, ypB, zlB, qrA, krA, ypA, zlA);
}

} // namespace

extern "C" void kernel_launch(void* const* d_in, const int* in_sizes, int n_in,
                              void* d_out, int out_size, void* d_ws, size_t ws_size,
                              hipStream_t stream) {
    const float* q          = (const float*)d_in[0];
    const float* k          = (const float*)d_in[1];
    const float* v          = (const float*)d_in[2];
    const float* pb         = (const float*)d_in[3];
    const float* se         = (const float*)d_in[4];
    const float* phase_base = (const float*)d_in[5];
    const float* phase_gain = (const float*)d_in[6];
    const float* y_pre      = (const float*)d_in[7];
    const float* z_pre      = (const float*)d_in[8];
    float* out              = (float*)d_out;

    const int positions = B_ * H_ * N_;          // 131072
    const int blocks    = positions / T_;        // 2048 blocks, 64 pos each
    dsqg_kernel<<<blocks, 256, 0, stream>>>(q, k, v, pb, se, phase_base,
                                            phase_gain, y_pre, z_pre, out);
}

// Round 9
// 172.981 us; speedup vs baseline: 1.0042x; 1.0042x over previous
//
#include <hip/hip_runtime.h>

// DSQG attention, J=12 causal offsets, f32.
// R10: bigger LDS window — serve d in {1,2,4,8,16,64,96} (7 of 12) from LDS.
// R9 post-mortem: per-wave MLP (pipeline) and wave count (R6) both gave ZERO;
// only traffic cuts moved time (R7b). Model: per-CU miss-path concurrency x
// latency wall (~60 lines in flight x 128 B / ~450 cy ~= 17 B/cy/CU). Only
// lever = fewer lines:
//   * block owns T=128 positions, 512 threads (8 waves); k,v rows
//     [P-96, P+127] (224 rows, 112 KB) in DYNAMIC LDS (115 KB total,
//     hipFuncSetAttribute; 1 block/CU). Global per position: q + 5k + 5v
//     (d in {192,384,512,768,1024}) = 11 rows vs 15 -> ~0.80x traffic.
//   * grid = 1024 = 4 x 256 CUs exactly (no tail); XCD swizzle keeps each
//     bh's blocks on one XCD (L2-local k/v re-reads).
//   * R9 macro pipeline kept (named ping-pong state, macro-instantiated):
//     A(j)=q,5k,y,z [8 ops] -> top vmcnt(3|2) -> dot -> B(j)=5v+vx [6] ->
//     prefetch A(j+1) [8] -> DPP+softmax -> tail vmcnt(8|0) -> epilogue.
//   * vx (rotation v ch0-3): LDS for lanes t8<=2 (dl in {16,64,96}),
//     global for t8>=3; select per lane.
// Carried: lane-parallel rotation, DPP 16-lane allreduce, max-free softmax,
// v_rcp normalize, se table in LDS, asm-pinned scalar preloads.

namespace {

constexpr int J   = 12;
constexpr int B_  = 2;
constexpr int H_  = 16;
constexpr int N_  = 4096;
constexpr int HD_ = 64;
constexpr int OFFS[J] = {1, 2, 4, 8, 16, 64, 96, 192, 384, 512, 768, 1024};
constexpr int T_   = 128;          // positions per block
constexpr int HALO = 96;           // window back-reach (covers d<=96)
constexpr int W_   = T_ + HALO;    // 224 staged rows: [P-96, P+127]
constexpr int LDS_KV = W_ * 16 * 16;              // bytes for one of kS/vS
constexpr int LDS_TOTAL = 2 * LDS_KV + J * 16 * 16;  // + seS = 117760 B

using f32x4 = __attribute__((ext_vector_type(4))) float;
using f32x2 = __attribute__((ext_vector_type(2))) float;

#define GLOAD4(dst, off, base)                                              \
    asm volatile("global_load_dwordx4 %0, %1, %2"                           \
                 : "=v"(dst) : "v"(off), "s"(base) : "memory")
#define GLOAD2(dst, off, base)                                              \
    asm volatile("global_load_dwordx2 %0, %1, %2"                           \
                 : "=v"(dst) : "v"(off), "s"(base) : "memory")

#define VMWAIT(N)                                                           \
    asm volatile("s_waitcnt vmcnt(" #N ")" ::: "memory");                   \
    __builtin_amdgcn_sched_barrier(0)

// p += dpp_mov(p); CTRL must be an ICE, hence the template.
template <int CTRL>
__device__ __forceinline__ float dpp_add(float x) {
    int s = __builtin_amdgcn_update_dpp(0, __builtin_bit_cast(int, x),
                                        CTRL, 0xF, 0xF, false);
    return x + __builtin_bit_cast(float, s);
}

// A-batch for position nn: q, 5 large-d k (i=7..11), y, z — 8 vmem ops in
// this exact order (vmcnt ledger depends on it).
#define ISSUEA(nn, QR, KR, YP, ZL) do {                                     \
    const int nA_ = (nn);                                                   \
    const uint32_t rbA_ = ((uint32_t)nA_ << 8) + gbl;                       \
    GLOAD4(QR, rbA_, qb);                                                   \
    _Pragma("unroll")                                                       \
    for (int i = 7; i < J; ++i) {                                           \
        const uint32_t oA_ = (nA_ >= OFFS[i])                               \
            ? (rbA_ - ((uint32_t)OFFS[i] << 8)) : gbl;                      \
        GLOAD4(KR[i - 7], oA_, kb);                                         \
    }                                                                       \
    const uint32_t nb8A_ = (uint32_t)nA_ << 3;                              \
    GLOAD2(YP, nb8A_, yb);                                                  \
    const uint32_t zoA_ = (nA_ >= dl) ? ((uint32_t)(nA_ - dl) << 3) : 0u;   \
    GLOAD2(ZL, zoA_, zb);                                                   \
} while (0)

// One pipeline iteration; TOPN/TAILN literal vmcnt counts, PREF literal 0/1.
#define ITERBODY(NVAL, TOPN, TAILN, PREF, QR, KR, YP, ZL, QRN, KRN, YPN, ZLN) \
do {                                                                        \
    const int n_ = (NVAL);                                                  \
    const uint32_t rowb_ = ((uint32_t)n_ << 8) + gbl;                       \
    VMWAIT(TOPN);                              /* q+5k of A(j) ready */     \
    const int rbase_ = n_ - P + HALO;          /* in [96, 223] */           \
    float p_[J];                                                            \
    _Pragma("unroll")                                                       \
    for (int i = 0; i < 7; ++i) {              /* d in {1..96} from LDS */  \
        const f32x4 kk  = kS[(rbase_ - OFFS[i]) * 16 + grp];                \
        const f32x4 seg = seS[i * 16 + grp];                                \
        float t = QR.x * (kk.x + seg.x);                                    \
        t = fmaf(QR.y, kk.y + seg.y, t);                                    \
        t = fmaf(QR.z, kk.z + seg.z, t);                                    \
        p_[i] = fmaf(QR.w, kk.w + seg.w, t);                                \
    }                                                                       \
    _Pragma("unroll")                                                       \
    for (int i = 7; i < J; ++i) {              /* large d from regs */      \
        const f32x4 kk  = KR[i - 7];                                        \
        const f32x4 seg = seS[i * 16 + grp];                                \
        float t = QR.x * (kk.x + seg.x);                                    \
        t = fmaf(QR.y, kk.y + seg.y, t);                                    \
        t = fmaf(QR.z, kk.z + seg.z, t);                                    \
        p_[i] = fmaf(QR.w, kk.w + seg.w, t);                                \
    }                                                                       \
    /* batch B(j): 5 large-d v + vx(global path) */                         \
    f32x4 vr_[5];                                                           \
    _Pragma("unroll")                                                       \
    for (int i = 7; i < J; ++i) {                                           \
        const uint32_t oB_ = (n_ >= OFFS[i])                                \
            ? (rowb_ - ((uint32_t)OFFS[i] << 8)) : gbl;                     \
        GLOAD4(vr_[i - 7], oB_, vb);                                        \
    }                                                                       \
    f32x4 vxg_;                                                             \
    const uint32_t vxo_ = ((t8 >= 3) && (n_ >= dl))                         \
        ? ((uint32_t)(n_ - dl) << 8) : 0u;                                  \
    GLOAD4(vxg_, vxo_, vb);                                                 \
    if (PREF) { ISSUEA(n_ + 32, QRN, KRN, YPN, ZLN); }                      \
    /* 16-lane allreduce (pure VALU DPP); covers B + A(j+1) latency */      \
    _Pragma("unroll")                                                       \
    for (int i = 0; i < J; ++i) {                                           \
        p_[i] = dpp_add<0xB1>(p_[i]);   /* quad_perm [1,0,3,2] : xor 1 */   \
        p_[i] = dpp_add<0x4E>(p_[i]);   /* quad_perm [2,3,0,1] : xor 2 */   \
        p_[i] = dpp_add<0x124>(p_[i]);  /* row_ror:4 */                     \
        p_[i] = dpp_add<0x128>(p_[i]);  /* row_ror:8 */                     \
    }                                                                       \
    float e_[J];                                                            \
    float sum_ = 0.f;                                                       \
    _Pragma("unroll")                                                       \
    for (int i = 0; i < J; ++i) {                                           \
        const float si = fmaf(p_[i], 0.125f, pbh[i]);                       \
        e_[i] = (n_ >= OFFS[i]) ? __expf(si) : 0.f;                         \
        sum_ += e_[i];                                                      \
    }                                                                       \
    /* vx LDS path for t8<=2 (dl in {16,64,96}; rows in window) */          \
    const int relv_ = (t8 <= 2) ? (rbase_ - dl) : 0;                        \
    const f32x4 vxl_ = vS[relv_ * 16];                                      \
    VMWAIT(TAILN);                 /* iter-j vmem done; A(j+1) in flight */ \
    const f32x4 vx_ = (t8 <= 2) ? vxl_ : vxg_;                              \
    /* lane-parallel rotation: lane handles offset i = 4 + t8 */            \
    const float s01_ = (t8 & 1) ? e_[5]  : e_[4];                           \
    const float s23_ = (t8 & 1) ? e_[7]  : e_[6];                           \
    const float s45_ = (t8 & 1) ? e_[9]  : e_[8];                           \
    const float s67_ = (t8 & 1) ? e_[11] : e_[10];                          \
    const float sA_  = (t8 & 2) ? s23_ : s01_;                              \
    const float sB_  = (t8 & 2) ? s67_ : s45_;                              \
    const float esel_ = (t8 & 4) ? sB_ : sA_;                               \
    const float th0_ = fmaf(pgn.x, YP.x * ZL.x, pbs.x);                     \
    const float th1_ = fmaf(pgn.y, YP.y * ZL.y, pbs.y);                     \
    const float c0_ = __cosf(th0_), s0_ = __sinf(th0_);                     \
    const float c1_ = __cosf(th1_), s1_ = __sinf(th1_);                     \
    f32x4 cx_;                                                              \
    cx_.x = esel_ * (c0_ * vx_.x - s0_ * vx_.y);                            \
    cx_.y = esel_ * (s0_ * vx_.x + c0_ * vx_.y);                            \
    cx_.z = esel_ * (c1_ * vx_.z - s1_ * vx_.w);                            \
    cx_.w = esel_ * (s1_ * vx_.z + c1_ * vx_.w);                            \
    cx_.x = dpp_add<0xB1>(cx_.x);  cx_.y = dpp_add<0xB1>(cx_.y);            \
    cx_.z = dpp_add<0xB1>(cx_.z);  cx_.w = dpp_add<0xB1>(cx_.w);            \
    cx_.x = dpp_add<0x4E>(cx_.x);  cx_.y = dpp_add<0x4E>(cx_.y);            \
    cx_.z = dpp_add<0x4E>(cx_.z);  cx_.w = dpp_add<0x4E>(cx_.w);            \
    cx_.x = dpp_add<0x124>(cx_.x); cx_.y = dpp_add<0x124>(cx_.y);           \
    cx_.z = dpp_add<0x124>(cx_.z); cx_.w = dpp_add<0x124>(cx_.w);           \
    /* weighted sum: i<7 from LDS window, i>=7 from regs */                 \
    float4 accl_ = make_float4(0.f, 0.f, 0.f, 0.f);                         \
    _Pragma("unroll")                                                       \
    for (int i = 0; i < 4; ++i) {                                           \
        const f32x4 vv = vS[(rbase_ - OFFS[i]) * 16 + grp];                 \
        accl_.x = fmaf(e_[i], vv.x, accl_.x);                               \
        accl_.y = fmaf(e_[i], vv.y, accl_.y);                               \
        accl_.z = fmaf(e_[i], vv.z, accl_.z);                               \
        accl_.w = fmaf(e_[i], vv.w, accl_.w);                               \
    }                                                                       \
    float4 acch_ = accl_;                                                   \
    _Pragma("unroll")                                                       \
    for (int i = 4; i < 7; ++i) {              /* d = 16, 64, 96 (LDS) */   \
        const f32x4 vv = vS[(rbase_ - OFFS[i]) * 16 + grp];                 \
        acch_.x = fmaf(e_[i], vv.x, acch_.x);                               \
        acch_.y = fmaf(e_[i], vv.y, acch_.y);                               \
        acch_.z = fmaf(e_[i], vv.z, acch_.z);                               \
        acch_.w = fmaf(e_[i], vv.w, acch_.w);                               \
    }                                                                       \
    _Pragma("unroll")                                                       \
    for (int i = 7; i < J; ++i) {                                           \
        acch_.x = fmaf(e_[i], vr_[i - 7].x, acch_.x);                       \
        acch_.y = fmaf(e_[i], vr_[i - 7].y, acch_.y);                       \
        acch_.z = fmaf(e_[i], vr_[i - 7].z, acch_.z);                       \
        acch_.w = fmaf(e_[i], vr_[i - 7].w, acch_.w);                       \
    }                                                                       \
    const bool lo_ = (grp == 0);                                            \
    float4 acc_;                                                            \
    acc_.x = lo_ ? accl_.x + cx_.x : acch_.x;                               \
    acc_.y = lo_ ? accl_.y + cx_.y : acch_.y;                               \
    acc_.z = lo_ ? accl_.z + cx_.z : acch_.z;                               \
    acc_.w = lo_ ? accl_.w + cx_.w : acch_.w;                               \
    float4 res_;                                                            \
    if (n_ >= 1) {                                                          \
        const float inv_ = __builtin_amdgcn_rcpf(sum_);                     \
        res_ = make_float4(acc_.x * inv_, acc_.y * inv_,                    \
                           acc_.z * inv_, acc_.w * inv_);                   \
    } else {                                                                \
        res_ = make_float4(0.f, 0.f, 0.f, 0.f);                             \
    }                                                                       \
    *(float4*)(ob + rowb_) = res_;   /* newest vmem op; bound by asm */     \
} while (0)

__global__ __launch_bounds__(512, 2) void dsqg_kernel(
    const float* __restrict__ q, const float* __restrict__ k,
    const float* __restrict__ v, const float* __restrict__ pb,
    const float* __restrict__ se, const float* __restrict__ phase_base,
    const float* __restrict__ phase_gain, const float* __restrict__ y_pre,
    const float* __restrict__ z_pre, float* __restrict__ out)
{
    extern __shared__ char smem[];
    f32x4* kS  = (f32x4*)smem;                        // 224 rows x 16 f32x4
    f32x4* vS  = (f32x4*)(smem + LDS_KV);             // 224 rows x 16 f32x4
    f32x4* seS = (f32x4*)(smem + 2 * LDS_KV);         // 12 x 16 f32x4

    // XCD-locality swizzle: 128 consecutive wid per XCD = 4 whole bh's.
    const int raw = blockIdx.x;
    const int per = gridDim.x >> 3;            // 1024/8 = 128
    const int wid = (raw & 7) * per + (raw >> 3);

    const int bh  = wid >> 5;                  // 32 blocks per (b,h)
    const int blk = wid & 31;
    const int h   = bh & (H_ - 1);
    const int P   = blk * T_;                  // first position of this block

    const int tid  = threadIdx.x;
    const int lane = tid & 63;
    const int wave = tid >> 6;                 // 0..7
    const int grp  = lane & 15;                // lane within position group
    const int sub  = lane >> 4;                // position-within-quad

    if (tid < J * 16) seS[tid] = ((const f32x4*)se)[tid];

    // uniform (SGPR) per-(b,h) base pointers
    const size_t bhbytes = (size_t)bh * (N_ * HD_ * 4);
    const char* qb = (const char*)q + bhbytes;
    const char* kb = (const char*)k + bhbytes;
    const char* vb = (const char*)v + bhbytes;
    char*       ob = (char*)out + bhbytes;
    const char* yb = (const char*)y_pre + (size_t)bh * (N_ * 8);
    const char* zb = (const char*)z_pre + (size_t)bh * (N_ * 8);

    // ---- stage k/v window [P-96, P+127] into LDS (7 x 512 thr x 16 B) ------
    {
        const int r0 = P - HALO;
#pragma unroll
        for (int t = 0; t < (W_ * 16) / 512; ++t) {
            const int idx = t * 512 + tid;     // 0..3583 (float4 index)
            const int row = idx >> 4;
            const int col = idx & 15;
            int gr = r0 + row;                 // clamp for first blocks
            gr = gr < 0 ? 0 : gr;
            const uint32_t go = ((uint32_t)gr << 8) + ((uint32_t)col << 4);
            kS[idx] = *(const f32x4*)(kb + go);
            vS[idx] = *(const f32x4*)(vb + go);
        }
    }

    // per-lane rotation offset dl = OFFS[4 + (grp&7)] via cndmask tree
    const int t8  = grp & 7;
    const int d01 = (t8 & 1) ? 64   : 16;
    const int d23 = (t8 & 1) ? 192  : 96;
    const int d45 = (t8 & 1) ? 512  : 384;
    const int d67 = (t8 & 1) ? 1024 : 768;
    const int dA  = (t8 & 2) ? d23 : d01;
    const int dB  = (t8 & 2) ? d67 : d45;
    const int dl  = (t8 & 4) ? dB : dA;

    const uint32_t pofs = (uint32_t)(t8 * H_ + h) << 3;    // [pi][h][2] f32
    const f32x2 pbs = *(const f32x2*)((const char*)phase_base + pofs);
    const f32x2 pgn = *(const f32x2*)((const char*)phase_gain + pofs);
    float pbh[J];
#pragma unroll
    for (int i = 0; i < J; ++i) pbh[i] = pb[i * H_ + h];

    // Force all compiler-tracked loads above to COMPLETE here, so the asm
    // vmcnt ledger below starts at zero (no reliance on barrier drain).
    asm volatile("" :: "v"(pbs.x), "v"(pbs.y), "v"(pgn.x), "v"(pgn.y));
    asm volatile("" :: "v"(pbh[0]), "v"(pbh[1]), "v"(pbh[2]), "v"(pbh[3]),
                       "v"(pbh[4]), "v"(pbh[5]), "v"(pbh[6]), "v"(pbh[7]),
                       "v"(pbh[8]), "v"(pbh[9]), "v"(pbh[10]), "v"(pbh[11]));

    __syncthreads();    // staging + seS visible

    const uint32_t gbl = (uint32_t)grp << 4;
    const int n0 = P + wave * 4 + sub;         // j advances by 32 positions

    // ---- software pipeline: named ping-pong A-state, macro-instantiated ----
    f32x4 qrA, qrB;
    f32x4 krA[5], krB[5];
    f32x2 ypA, ypB, zlA, zlB;

    ISSUEA(n0, qrA, krA, ypA, zlA);

    ITERBODY(n0,      2, 8, 1, qrA, krA, ypA, zlA, qrB, krB, ypB, zlB);
    ITERBODY(n0 + 32, 3, 8, 1, qrB, krB, ypB, zlB, qrA, krA, ypA, zlA);
    ITERBODY(n0 + 64, 3, 8, 1, qrA, krA, ypA, zlA, qrB, krB, ypB, zlB);
    ITERBODY(n0 + 96, 3, 0, 0, qrB, krB, ypB, zlB, qrA, krA, ypA, zlA);
}

} // namespace

extern "C" void kernel_launch(void* const* d_in, const int* in_sizes, int n_in,
                              void* d_out, int out_size, void* d_ws, size_t ws_size,
                              hipStream_t stream) {
    const float* q          = (const float*)d_in[0];
    const float* k          = (const float*)d_in[1];
    const float* v          = (const float*)d_in[2];
    const float* pb         = (const float*)d_in[3];
    const float* se         = (const float*)d_in[4];
    const float* phase_base = (const float*)d_in[5];
    const float* phase_gain = (const float*)d_in[6];
    const float* y_pre      = (const float*)d_in[7];
    const float* z_pre      = (const float*)d_in[8];
    float* out              = (float*)d_out;

    static bool attr_set = false;
    if (!attr_set) {
        (void)hipFuncSetAttribute((const void*)dsqg_kernel,
                                  hipFuncAttributeMaxDynamicSharedMemorySize,
                                  LDS_TOTAL);
        attr_set = true;
    }

    const int positions = B_ * H_ * N_;          // 131072
    const int blocks    = positions / T_;        // 1024 blocks, 128 pos each
    dsqg_kernel<<<blocks, 512, LDS_TOTAL, stream>>>(q, k, v, pb, se,
                                                    phase_base, phase_gain,
                                                    y_pre, z_pre, out);
}